// Round 1
// baseline (739.008 us; speedup 1.0000x reference)
//
#include <hip/hip_runtime.h>
#include <hip/hip_bf16.h>

#define NB 256        // n_bases
#define IDIM 768      // 3*16*16 features
#define NPP 729       // patches per image (27*27)
#define PSTRIDE 736   // padded rows per image (23*32)
#define MROWS 32      // patch rows per block
#define BLKPI 23      // blocks per image
#define NIMG 64
#define ITERS 50

typedef float f32x4 __attribute__((ext_vector_type(4)));
typedef short bf16x8 __attribute__((ext_vector_type(8)));

__device__ __forceinline__ short f2bf(float x) {
  union { float f; unsigned u; } v; v.f = x;
  unsigned r = v.u + 0x7FFFu + ((v.u >> 16) & 1u);   // round-to-nearest-even
  return (short)(r >> 16);
}

__device__ __forceinline__ float softshrink(float u) {
  float t = fmaxf(fabsf(u) - 0.5f, 0.0f);
  return copysignf(t, u);
}

// ---------------- Kernel 1: D -> bf16 copy, gram = D D^T - I (bf16) ----------
__global__ __launch_bounds__(256) void k_prep(const float* __restrict__ D,
                                              short* __restrict__ Dbf,
                                              short* __restrict__ gram) {
  __shared__ float drow[IDIM];
  int i = blockIdx.x;
  int t = threadIdx.x;
  for (int f = t; f < IDIM; f += 256) {
    float v = D[(size_t)i * IDIM + f];
    drow[f] = v;
    Dbf[(size_t)i * IDIM + f] = f2bf(v);
  }
  __syncthreads();
  int j = t;
  float s = 0.f;
  for (int k = 0; k < IDIM; ++k) s += drow[k] * D[(size_t)j * IDIM + k];
  if (j == i) s -= 1.0f;
  gram[i * NB + j] = f2bf(s);
}

// ---------------- Kernel 2: unfold + standardize + b = p @ D^T ---------------
__global__ __launch_bounds__(256) void k_patches_b(const float* __restrict__ img,
                                                   const short* __restrict__ Dbf,
                                                   float* __restrict__ bbuf) {
  __shared__ float P[MROWS][772];          // +4 pad -> conflict-free b128 reads
  __shared__ float s_mean[MROWS], s_inv[MROWS];
  int blk = blockIdx.x;    // 0..22
  int im  = blockIdx.y;    // 0..63
  int t = threadIdx.x;
  int p0 = blk * MROWS;

  // stage 32 patches x 768 feats (feature order: c*256 + ph*16 + pw)
  for (int c3 = 0; c3 < 3; ++c3) {
    int f = t + c3 * 256;
    int ch = f >> 8, rem = f & 255, ph = rem >> 4, pw = rem & 15;
    const float* base = img + ((size_t)(im * 3 + ch)) * 224 * 224;
    for (int p = 0; p < MROWS; ++p) {
      int patch = p0 + p;
      float v = 0.f;
      if (patch < NPP) {
        int py = patch / 27, px = patch % 27;
        v = base[(py * 8 + ph) * 224 + px * 8 + pw];
      }
      P[p][f] = v;
    }
  }
  __syncthreads();

  // per-patch mean / 1/(std+1e-8), ddof=1 ; 8 threads per patch
  {
    int p = t >> 3, f0 = t & 7;
    float s = 0.f, ss = 0.f;
    for (int k = f0; k < IDIM; k += 8) { float v = P[p][k]; s += v; ss += v * v; }
    #pragma unroll
    for (int d = 1; d < 8; d <<= 1) { s += __shfl_xor(s, d); ss += __shfl_xor(ss, d); }
    if (f0 == 0) {
      float mean = s * (1.0f / 768.0f);
      float var = (ss - s * mean) * (1.0f / 767.0f);
      float sd = sqrtf(fmaxf(var, 0.f));
      s_mean[p] = mean;
      s_inv[p] = 1.0f / (sd + 1e-8f);
    }
  }
  __syncthreads();
  for (int c3 = 0; c3 < 3; ++c3) {
    int f = t + c3 * 256;
    for (int p = 0; p < MROWS; ++p)
      P[p][f] = (P[p][f] - s_mean[p]) * s_inv[p];
  }
  __syncthreads();

  // GEMM: C[32][256] = P[32][768] @ Dbf^T. wave w owns col-tiles 4w..4w+3
  int w = t >> 6, l = t & 63, lr = l & 15, q = l >> 4;
  f32x4 acc[2][4];
  #pragma unroll
  for (int i = 0; i < 2; ++i)
    #pragma unroll
    for (int j = 0; j < 4; ++j) acc[i][j] = (f32x4){0.f, 0.f, 0.f, 0.f};

  for (int kc = 0; kc < 24; ++kc) {
    bf16x8 af[2];
    #pragma unroll
    for (int rt = 0; rt < 2; ++rt) {
      const float4* src = reinterpret_cast<const float4*>(&P[rt * 16 + lr][kc * 32 + q * 8]);
      float4 x = src[0], y = src[1];
      bf16x8 v;
      v[0] = f2bf(x.x); v[1] = f2bf(x.y); v[2] = f2bf(x.z); v[3] = f2bf(x.w);
      v[4] = f2bf(y.x); v[5] = f2bf(y.y); v[6] = f2bf(y.z); v[7] = f2bf(y.w);
      af[rt] = v;
    }
    bf16x8 bfr[4];
    #pragma unroll
    for (int c = 0; c < 4; ++c) {
      int col = (w * 4 + c) * 16 + lr;  // B[k][n] = D[n][k]: k-contiguous in D row
      bfr[c] = *reinterpret_cast<const bf16x8*>(&Dbf[(size_t)col * IDIM + kc * 32 + q * 8]);
    }
    #pragma unroll
    for (int rt = 0; rt < 2; ++rt)
      #pragma unroll
      for (int c = 0; c < 4; ++c)
        acc[rt][c] = __builtin_amdgcn_mfma_f32_16x16x32_bf16(af[rt], bfr[c], acc[rt][c], 0, 0, 0);
  }

  size_t rowbase = ((size_t)im * PSTRIDE + p0) * NB;
  #pragma unroll
  for (int rt = 0; rt < 2; ++rt)
    #pragma unroll
    for (int c = 0; c < 4; ++c)
      #pragma unroll
      for (int r = 0; r < 4; ++r) {
        int row = rt * 16 + q * 4 + r;          // C/D: row=(l>>4)*4+reg
        int col = (w * 4 + c) * 16 + lr;        //      col=l&15
        bbuf[rowbase + (size_t)row * NB + col] = acc[rt][c][r];
      }
}

// ---------------- Kernel 3: 50 LCA iterations, u in registers ----------------
__global__ __launch_bounds__(256, 2) void k_lca(const float* __restrict__ bbuf,
                                                const short* __restrict__ gram,
                                                float* __restrict__ partial) {
  __shared__ short albuf[MROWS * NB];   // 16KB, XOR-swizzled a (bf16)
  int blk = blockIdx.x, im = blockIdx.y;
  int t = threadIdx.x;
  int w = t >> 6, l = t & 63, lr = l & 15, q = l >> 4;
  int p0 = blk * MROWS;

  float u[2][4][4], bb[2][4][4];
  size_t rowbase = ((size_t)im * PSTRIDE + p0) * NB;
  #pragma unroll
  for (int rt = 0; rt < 2; ++rt)
    #pragma unroll
    for (int c = 0; c < 4; ++c)
      #pragma unroll
      for (int r = 0; r < 4; ++r) {
        int row = rt * 16 + q * 4 + r, col = (w * 4 + c) * 16 + lr;
        bb[rt][c][r] = bbuf[rowbase + (size_t)row * NB + col];
        u[rt][c][r] = 0.f;
      }

  for (int it = 0; it < ITERS; ++it) {
    // a = softshrink(u) -> LDS (swizzle: byte ^= ((row>>2)&3)<<5) conflict-free
    #pragma unroll
    for (int rt = 0; rt < 2; ++rt)
      #pragma unroll
      for (int c = 0; c < 4; ++c)
        #pragma unroll
        for (int r = 0; r < 4; ++r) {
          int row = rt * 16 + q * 4 + r, col = (w * 4 + c) * 16 + lr;
          int byte = (row * 512 + col * 2) ^ (((row >> 2) & 3) << 5);
          albuf[byte >> 1] = f2bf(softshrink(u[rt][c][r]));
        }
    __syncthreads();

    f32x4 acc[2][4];
    #pragma unroll
    for (int i = 0; i < 2; ++i)
      #pragma unroll
      for (int j = 0; j < 4; ++j) acc[i][j] = (f32x4){0.f, 0.f, 0.f, 0.f};

    #pragma unroll
    for (int kc = 0; kc < 8; ++kc) {
      bf16x8 af[2];
      #pragma unroll
      for (int rt = 0; rt < 2; ++rt) {
        int row = rt * 16 + lr;
        int byte = (row * 512 + (kc * 32 + q * 8) * 2) ^ (((row >> 2) & 3) << 5);
        af[rt] = *reinterpret_cast<const bf16x8*>(reinterpret_cast<const char*>(albuf) + byte);
      }
      bf16x8 gf[4];
      #pragma unroll
      for (int c = 0; c < 4; ++c) {
        int col = (w * 4 + c) * 16 + lr;  // gram symmetric: B[k][n]=gram[n][k]
        gf[c] = *reinterpret_cast<const bf16x8*>(&gram[col * NB + kc * 32 + q * 8]);
      }
      #pragma unroll
      for (int rt = 0; rt < 2; ++rt)
        #pragma unroll
        for (int c = 0; c < 4; ++c)
          acc[rt][c] = __builtin_amdgcn_mfma_f32_16x16x32_bf16(af[rt], gf[c], acc[rt][c], 0, 0, 0);
    }
    __syncthreads();

    #pragma unroll
    for (int rt = 0; rt < 2; ++rt)
      #pragma unroll
      for (int c = 0; c < 4; ++c)
        #pragma unroll
        for (int r = 0; r < 4; ++r)
          u[rt][c][r] += 0.01f * (bb[rt][c][r] - u[rt][c][r] - acc[rt][c][r]);
  }

  // codes = softshrink(u); masked max over the block's valid rows
  #pragma unroll
  for (int c = 0; c < 4; ++c) {
    float m = -3.402823466e38f;
    #pragma unroll
    for (int rt = 0; rt < 2; ++rt)
      #pragma unroll
      for (int r = 0; r < 4; ++r) {
        int row = rt * 16 + q * 4 + r;
        if (p0 + row < NPP) m = fmaxf(m, softshrink(u[rt][c][r]));
      }
    m = fmaxf(m, __shfl_xor(m, 16));
    m = fmaxf(m, __shfl_xor(m, 32));
    if (l < 16) partial[((size_t)im * BLKPI + blk) * NB + (w * 4 + c) * 16 + lr] = m;
  }
}

// ---------------- Kernel 4: reduce 23 partials per image ---------------------
__global__ __launch_bounds__(256) void k_pool(const float* __restrict__ partial,
                                              float* __restrict__ out) {
  int im = blockIdx.x, n = threadIdx.x;
  float m = -3.402823466e38f;
  for (int b = 0; b < BLKPI; ++b)
    m = fmaxf(m, partial[((size_t)im * BLKPI + b) * NB + n]);
  out[im * NB + n] = m;
}

extern "C" void kernel_launch(void* const* d_in, const int* in_sizes, int n_in,
                              void* d_out, int out_size, void* d_ws, size_t ws_size,
                              hipStream_t stream) {
  const float* img = (const float*)d_in[0];
  const float* D   = (const float*)d_in[1];
  // d_in[2] = stride (8, fixed by the reference setup)

  char* ws = (char*)d_ws;
  short* gram   = (short*)(ws);                    // 256*256*2   = 131072 B
  short* Dbf    = (short*)(ws + 131072);           // 256*768*2   = 393216 B
  float* bbuf   = (float*)(ws + 524288);           // 64*736*256*4 = 48234496 B
  float* partial= (float*)(ws + 48758784);         // 64*23*256*4 = 1507328 B
  float* out = (float*)d_out;

  hipLaunchKernelGGL(k_prep, dim3(256), dim3(256), 0, stream, D, Dbf, gram);
  hipLaunchKernelGGL(k_patches_b, dim3(BLKPI, NIMG), dim3(256), 0, stream, img, Dbf, bbuf);
  hipLaunchKernelGGL(k_lca, dim3(BLKPI, NIMG), dim3(256), 0, stream, bbuf, gram, partial);
  hipLaunchKernelGGL(k_pool, dim3(NIMG), dim3(256), 0, stream, partial, out);
}